// Round 3
// baseline (2947.778 us; speedup 1.0000x reference)
//
#include <hip/hip_runtime.h>

// Problem constants (fixed by the reference)
#define HID 2048
#define SEQ 2048
#define NB 2
#define NHD 16
#define HD 128
#define FF 5632
#define MROWS 4096  // NB*SEQ

typedef __bf16 bf16x8 __attribute__((ext_vector_type(8)));
typedef float f32x4 __attribute__((ext_vector_type(4)));
typedef unsigned short u16;
typedef unsigned int u32;
typedef unsigned long long u64;

__device__ __forceinline__ u16 f2bf(float f) {
  u32 u = __float_as_uint(f);
  u += 0x7fffu + ((u >> 16) & 1u);   // RNE
  return (u16)(u >> 16);
}
__device__ __forceinline__ float bf2f(u16 h) {
  return __uint_as_float(((u32)h) << 16);
}
__device__ __forceinline__ void gld16(const void* g, void* l) {
  // async global->LDS, 16B per lane; LDS dest = wave-uniform base + lane*16
  __builtin_amdgcn_global_load_lds((__attribute__((address_space(1))) void*)g,
                                   (__attribute__((address_space(3))) void*)l, 16, 0, 0);
}

// ---------------- RMSNorm: fp32 [rows][2048] -> bf16 ----------------
__global__ __launch_bounds__(256) void rmsnorm_k(const float* __restrict__ x,
                                                 const float* __restrict__ sc,
                                                 u16* __restrict__ out) {
  __shared__ float red[4];
  const int row = blockIdx.x, t = threadIdx.x;
  const float4* xr = (const float4*)(x + (size_t)row * HID);
  float4 a = xr[t], b = xr[t + 256];
  float ss = a.x*a.x + a.y*a.y + a.z*a.z + a.w*a.w
           + b.x*b.x + b.y*b.y + b.z*b.z + b.w*b.w;
#pragma unroll
  for (int o = 1; o < 64; o <<= 1) ss += __shfl_xor(ss, o);
  if ((t & 63) == 0) red[t >> 6] = ss;
  __syncthreads();
  float tot = red[0] + red[1] + red[2] + red[3];
  float r = rsqrtf(tot * (1.0f / HID) + 1e-5f);
  const float4* scp = (const float4*)sc;
  float4 s0 = scp[t], s1 = scp[t + 256];
  u32 p0 = (u32)f2bf(a.x*r*s0.x) | ((u32)f2bf(a.y*r*s0.y) << 16);
  u32 p1 = (u32)f2bf(a.z*r*s0.z) | ((u32)f2bf(a.w*r*s0.w) << 16);
  u32 p2 = (u32)f2bf(b.x*r*s1.x) | ((u32)f2bf(b.y*r*s1.y) << 16);
  u32 p3 = (u32)f2bf(b.z*r*s1.z) | ((u32)f2bf(b.w*r*s1.w) << 16);
  u32* op = (u32*)(out + (size_t)row * HID);
  op[t*2] = p0; op[t*2+1] = p1;
  op[512 + t*2] = p2; op[512 + t*2 + 1] = p3;
}

// ------------- transpose+convert: fp32 W[R][C] -> bf16 Wt[C][R] -------------
__global__ __launch_bounds__(256) void transpose_cvt_k(const float* __restrict__ W,
                                                       u16* __restrict__ Wt,
                                                       int R, int C) {
  __shared__ float tile[32][33];
  const int tx = threadIdx.x & 31, ty = threadIdx.x >> 5;
  const int bc = blockIdx.x * 32, br = blockIdx.y * 32;
#pragma unroll
  for (int i = 0; i < 4; ++i)
    tile[ty + i*8][tx] = W[(size_t)(br + ty + i*8) * C + bc + tx];
  __syncthreads();
#pragma unroll
  for (int i = 0; i < 4; ++i)
    Wt[(size_t)(bc + ty + i*8) * R + br + tx] = f2bf(tile[tx][ty + i*8]);
}

// ---------------- RoPE in place on qb||kb, each [B,H,S,D] bf16 ----------------
__global__ __launch_bounds__(256) void rope2_k(u16* __restrict__ qk, const int* __restrict__ pos) {
  const u32 i = blockIdx.x * 256 + threadIdx.x;  // 2*B*H*S*64 pairs
  const int d2 = i & 63;
  const int s = (i >> 6) & 2047;
  const int bh2 = i >> 17;            // 0..31 = Q heads, 32..63 = K heads
  const int b = (bh2 >> 4) & 1;
  const float p = (float)pos[(size_t)b * SEQ + s];
  const float ang = p * exp2f(-(float)d2 * 0.2958057589f);  // theta^(-d2/64)
  float sv, cv;
  sincosf(ang, &sv, &cv);
  u32* ptr = (u32*)(qk + ((size_t)bh2 * SEQ + s) * HD) + d2;
  u32 u = *ptr;
  float x0 = bf2f((u16)(u & 0xffff)), x1 = bf2f((u16)(u >> 16));
  float o0 = x0 * cv - x1 * sv;
  float o1 = x1 * cv + x0 * sv;
  *ptr = (u32)f2bf(o0) | ((u32)f2bf(o1) << 16);
}

// ---------------- GEMM: C[M][N] = A[M][K] * Bt[N][K]^T, bf16 in, fp32 acc ----------------
// m97 structure: 128x128 tile, 4 waves of 64x64, BK=32, global_load_lds staging.
// EPI: 2 = fp32 out = addsrc + acc; 3 = bf16 out = silu(acc);
//      4 = bf16 out = bf2f(mulsrc)*acc (in-place ok)
//      6 = fused QKV: n<2048 -> Q scatter [B,H,S,D]; <4096 -> K scatter; else V^T [B,H,D,S]
template <int EPI>
__global__ __launch_bounds__(256, 2) void gemm_k(const u16* __restrict__ A,
                                                 const u16* __restrict__ Bt,
                                                 int N, int K,
                                                 const float* addsrc,
                                                 const u16* mulsrc,
                                                 void* outp) {
  __shared__ __align__(16) u16 As[128 * 32];
  __shared__ __align__(16) u16 Bs[128 * 32];
  const int tid = threadIdx.x, lane = tid & 63, wid = tid >> 6;
  const int lr = lane & 15, lg = lane >> 4;
  const int wr = wid >> 1, wc = wid & 1;
  const int mt = blockIdx.y * 128, nt = blockIdx.x * 128;

  const f32x4 fz = {0.f, 0.f, 0.f, 0.f};
  f32x4 acc[4][4];
#pragma unroll
  for (int i = 0; i < 4; ++i)
#pragma unroll
    for (int j = 0; j < 4; ++j) acc[i][j] = fz;

  const int r0 = wid * 32 + (lane >> 2);     // chunk0 row
  const int c0 = (lane & 3) * 8;             // chunk0 col
  u16* ldsA0 = As + wid * 1024;              // wave-uniform bases
  u16* ldsA1 = As + wid * 1024 + 512;
  u16* ldsB0 = Bs + wid * 1024;
  u16* ldsB1 = Bs + wid * 1024 + 512;
  const u16* Abase = A + (size_t)mt * K;
  const u16* Bbase = Bt + (size_t)nt * K;

  for (int kt = 0; kt < K; kt += 32) {
    gld16(Abase + (size_t)r0 * K + kt + c0, ldsA0);
    gld16(Abase + (size_t)(r0 + 16) * K + kt + c0, ldsA1);
    gld16(Bbase + (size_t)r0 * K + kt + c0, ldsB0);
    gld16(Bbase + (size_t)(r0 + 16) * K + kt + c0, ldsB1);
    __syncthreads();
    bf16x8 af[4], bfr[4];
#pragma unroll
    for (int mi = 0; mi < 4; ++mi)
      af[mi] = *(const bf16x8*)(As + (wr * 64 + mi * 16 + lr) * 32 + lg * 8);
#pragma unroll
    for (int ni = 0; ni < 4; ++ni)
      bfr[ni] = *(const bf16x8*)(Bs + (wc * 64 + ni * 16 + lr) * 32 + lg * 8);
#pragma unroll
    for (int mi = 0; mi < 4; ++mi)
#pragma unroll
      for (int ni = 0; ni < 4; ++ni)
        acc[mi][ni] = __builtin_amdgcn_mfma_f32_16x16x32_bf16(af[mi], bfr[ni], acc[mi][ni], 0, 0, 0);
    __syncthreads();
  }

#pragma unroll
  for (int mi = 0; mi < 4; ++mi) {
#pragma unroll
    for (int ni = 0; ni < 4; ++ni) {
      const int gr0 = mt + wr * 64 + mi * 16 + lg * 4;
      const int gc = nt + wc * 64 + ni * 16 + lr;
      f32x4 v = acc[mi][ni];
      if (EPI == 6) {
        const int sel = gc >> 11, cc = gc & 2047, hh = cc >> 7, d = cc & 127;
        u16* base = (u16*)outp;
        const int b = gr0 >> 11, s0 = gr0 & 2047;
        if (sel == 2) {  // V^T [B,H,D,S]: 4 consecutive s in one u64
          u64 w = (u64)f2bf(v[0]) | ((u64)f2bf(v[1]) << 16)
                | ((u64)f2bf(v[2]) << 32) | ((u64)f2bf(v[3]) << 48);
          *(u64*)(base + (size_t)2 * MROWS * HID
                  + ((size_t)((b * NHD + hh) * HD + d)) * SEQ + s0) = w;
        } else {         // Q/K [B,H,S,D]
          u16* qk = base + (size_t)sel * MROWS * HID;
#pragma unroll
          for (int r = 0; r < 4; ++r)
            qk[((((size_t)(b * NHD + hh)) * SEQ + s0 + r) << 7) + d] = f2bf(v[r]);
        }
        continue;
      }
#pragma unroll
      for (int r = 0; r < 4; ++r) {
        const int gr = gr0 + r;
        const float val = v[r];
        if (EPI == 2) {
          const size_t o = (size_t)gr * N + gc;
          ((float*)outp)[o] = addsrc[o] + val;
        } else if (EPI == 3) {
          const size_t o = (size_t)gr * N + gc;
          ((u16*)outp)[o] = f2bf(val / (1.f + __expf(-val)));
        } else if (EPI == 4) {
          const size_t o = (size_t)gr * N + gc;
          ((u16*)outp)[o] = f2bf(bf2f(mulsrc[o]) * val);
        }
      }
    }
  }
}

// ---------------- Flash attention v3: transposed geometry + swizzled LDS staging ----------------
// Block = 128 q rows x whole-row scan in 64-key tiles. Wave owns q groups
// {q0, q0+64} (16 rows each) to even causal imbalance. K tile and V^T tile
// staged via async global_load_lds into XOR-swizzled LDS slots so the MFMA
// A-frag ds_read_b128 patterns are conflict-free. S^T = K*Q^T (softmax =
// 2 shuffles, alpha per-lane scalar), O^T = V^T*P^T, P^T through per-wave LDS.
__global__ __launch_bounds__(256, 2) void attn3_k(const u16* __restrict__ Q,
                                                  const u16* __restrict__ Kg,
                                                  const u16* __restrict__ Vtg,
                                                  u16* __restrict__ out) {
  __shared__ __align__(16) u16 Ks[64 * 128];   // 1024 slots of 8 u16, swizzled
  __shared__ __align__(16) u16 Vs[128 * 64];   // 1024 slots of 8 u16, swizzled
  __shared__ __align__(16) u16 Pl[4][32 * 72]; // per-wave P^T[q][key], stride 72
  const int tid = threadIdx.x, lane = tid & 63, wid = tid >> 6;
  const int lq = lane & 15, lg = lane >> 4;
  const int bh = blockIdx.y, b = bh >> 4, h = bh & 15;
  const int qt = (int)gridDim.x - 1 - (int)blockIdx.x;  // heavy blocks first
  const u16* Qp = Q + (size_t)bh * SEQ * HD;
  const u16* Kp = Kg + (size_t)bh * SEQ * HD;
  const u16* Vp = Vtg + (size_t)bh * HD * SEQ;
  u16* Pw = Pl[wid];
  const int qg0 = qt * 128 + wid * 16;
  const int qg1 = qg0 + 64;
  const int q0 = qg0 + lq, q1 = qg1 + lq;

  // Q as B-operand: B[k=d=lg*8+j][n=q=lq]
  bf16x8 qf0[4], qf1[4];
#pragma unroll
  for (int t = 0; t < 4; ++t) {
    qf0[t] = *(const bf16x8*)(Qp + (size_t)q0 * HD + t * 32 + lg * 8);
    qf1[t] = *(const bf16x8*)(Qp + (size_t)q1 * HD + t * 32 + lg * 8);
  }

  const f32x4 fz = {0.f, 0.f, 0.f, 0.f};
  f32x4 o0[8], o1[8];  // O^T[d][q]: lane holds d = dt*16 + lg*4 + r, q = lq
#pragma unroll
  for (int i = 0; i < 8; ++i) { o0[i] = fz; o1[i] = fz; }
  float m0 = -1e30f, l0 = 0.f, m1 = -1e30f, l1 = 0.f;
  const float scale = 0.08838834764831845f;  // 1/sqrt(128)

  const int kend = qt * 128 + 128;
  for (int kt = 0; kt < kend; kt += 64) {
    // ---- stage K tile: slot f = key*16 + (c ^ (key&15)), c = d/8 ----
#pragma unroll
    for (int i = 0; i < 4; ++i) {
      const int s = i * 256 + tid;
      const int k = s >> 4, c = (s & 15) ^ (k & 15);
      gld16(Kp + (size_t)(kt + k) * HD + c * 8, Ks + (size_t)(i * 256 + (tid & ~63)) * 8);
    }
    // ---- stage V^T tile: slot f = d*8 + (kc ^ (d&7)), kc = key/8 ----
#pragma unroll
    for (int i = 0; i < 4; ++i) {
      const int s = i * 256 + tid;
      const int d = s >> 3, kc = (s & 7) ^ (d & 7);
      gld16(Vp + (size_t)d * SEQ + kt + kc * 8, Vs + (size_t)(i * 256 + (tid & ~63)) * 8);
    }
    __syncthreads();

    // active 16-key subtiles per q-group (wave-uniform)
    int nmt1 = 0, nmt0 = 0;
    if (kt <= qg1 + 15) { nmt1 = ((qg1 + 15 - kt) >> 4) + 1; if (nmt1 > 4) nmt1 = 4; }
    if (kt <= qg0 + 15) { nmt0 = ((qg0 + 15 - kt) >> 4) + 1; if (nmt0 > 4) nmt0 = 4; }

    if (nmt1 > 0) {
      // ---- S^T = K*Q^T, kf shared across both q-groups ----
      f32x4 sc0[4], sc1[4];
#pragma unroll
      for (int mtv = 0; mtv < 4; ++mtv) {
        if (mtv < nmt1) {
          f32x4 a0 = fz, a1 = fz;
          const int key = mtv * 16 + lq;
          const int kbase = key * 16;
#pragma unroll
          for (int t = 0; t < 4; ++t) {
            const bf16x8 kf = *(const bf16x8*)(Ks + (size_t)(kbase + ((4 * t + lg) ^ (key & 15))) * 8);
            a1 = __builtin_amdgcn_mfma_f32_16x16x32_bf16(kf, qf1[t], a1, 0, 0, 0);
            if (mtv < nmt0)
              a0 = __builtin_amdgcn_mfma_f32_16x16x32_bf16(kf, qf0[t], a0, 0, 0, 0);
          }
          sc1[mtv] = a1;
          if (mtv < nmt0) sc0[mtv] = a0;
        }
      }
      // ---- softmax (per group; keys live in regs+lg: 2 shuffles) ----
      float mx0 = -1e30f, mx1 = -1e30f;
#pragma unroll
      for (int mtv = 0; mtv < 4; ++mtv) {
#pragma unroll
        for (int r = 0; r < 4; ++r) {
          const int key = kt + mtv * 16 + lg * 4 + r;
          if (mtv < nmt1) {
            float v = sc1[mtv][r] * scale;
            v = (key <= q1) ? v : -1e30f;
            sc1[mtv][r] = v; mx1 = fmaxf(mx1, v);
          }
          if (mtv < nmt0) {
            float v = sc0[mtv][r] * scale;
            v = (key <= q0) ? v : -1e30f;
            sc0[mtv][r] = v; mx0 = fmaxf(mx0, v);
          }
        }
      }
      mx1 = fmaxf(mx1, __shfl_xor(mx1, 16)); mx1 = fmaxf(mx1, __shfl_xor(mx1, 32));
      mx0 = fmaxf(mx0, __shfl_xor(mx0, 16)); mx0 = fmaxf(mx0, __shfl_xor(mx0, 32));
      const float mn1 = fmaxf(m1, mx1);
      const float mn0 = fmaxf(m0, mx0);
      float ts0 = 0.f, ts1 = 0.f;
#pragma unroll
      for (int mtv = 0; mtv < 4; ++mtv)
#pragma unroll
        for (int r = 0; r < 4; ++r) {
          if (mtv < nmt1) { const float e = __expf(sc1[mtv][r] - mn1); sc1[mtv][r] = e; ts1 += e; }
          if (mtv < nmt0) { const float e = __expf(sc0[mtv][r] - mn0); sc0[mtv][r] = e; ts0 += e; }
        }
      ts1 += __shfl_xor(ts1, 16); ts1 += __shfl_xor(ts1, 32);
      ts0 += __shfl_xor(ts0, 16); ts0 += __shfl_xor(ts0, 32);
      const float al1 = __expf(m1 - mn1);
      const float al0 = __expf(m0 - mn0);
      m1 = mn1; l1 = l1 * al1 + ts1;
      m0 = mn0; l0 = l0 * al0 + ts0;
#pragma unroll
      for (int i = 0; i < 8; ++i) {
        o1[i][0] *= al1; o1[i][1] *= al1; o1[i][2] *= al1; o1[i][3] *= al1;
        if (nmt0 > 0) { o0[i][0] *= al0; o0[i][1] *= al0; o0[i][2] *= al0; o0[i][3] *= al0; }
      }
      // ---- P^T -> per-wave LDS (pad stride 72 -> 2-way max) ----
      const int nks1 = (nmt1 + 1) >> 1, nks0 = (nmt0 + 1) >> 1;
#pragma unroll
      for (int mtv = 0; mtv < 4; ++mtv) {
        if (mtv < nks1 * 2) {
          u64 w = 0;
          if (mtv < nmt1)
            w = (u64)f2bf(sc1[mtv][0]) | ((u64)f2bf(sc1[mtv][1]) << 16)
              | ((u64)f2bf(sc1[mtv][2]) << 32) | ((u64)f2bf(sc1[mtv][3]) << 48);
          *(u64*)(Pw + (16 + lq) * 72 + mtv * 16 + lg * 4) = w;
        }
        if (mtv < nks0 * 2) {
          u64 w = 0;
          if (mtv < nmt0)
            w = (u64)f2bf(sc0[mtv][0]) | ((u64)f2bf(sc0[mtv][1]) << 16)
              | ((u64)f2bf(sc0[mtv][2]) << 32) | ((u64)f2bf(sc0[mtv][3]) << 48);
          *(u64*)(Pw + lq * 72 + mtv * 16 + lg * 4) = w;
        }
      }
      asm volatile("s_waitcnt lgkmcnt(0)\n" ::: "memory");  // same-wave write->read
      // ---- O^T += V^T * P^T, vf shared across both q-groups ----
#pragma unroll
      for (int ks = 0; ks < 2; ++ks) {
        if (ks < nks1) {
          const bf16x8 pf1v = *(const bf16x8*)(Pw + (16 + lq) * 72 + ks * 32 + lg * 8);
          bf16x8 pf0v;
          if (ks < nks0) pf0v = *(const bf16x8*)(Pw + lq * 72 + ks * 32 + lg * 8);
#pragma unroll
          for (int dt = 0; dt < 8; ++dt) {
            const int d = dt * 16 + lq;
            const bf16x8 vf = *(const bf16x8*)(Vs + (size_t)(d * 8 + ((4 * ks + lg) ^ (d & 7))) * 8);
            o1[dt] = __builtin_amdgcn_mfma_f32_16x16x32_bf16(vf, pf1v, o1[dt], 0, 0, 0);
            if (ks < nks0)
              o0[dt] = __builtin_amdgcn_mfma_f32_16x16x32_bf16(vf, pf0v, o0[dt], 0, 0, 0);
          }
        }
      }
    }
    __syncthreads();
  }

  // ---- epilogue: O^T lane holds d = dt*16+lg*4+r, q = lq ----
  const float inv0 = 1.f / l0, inv1 = 1.f / l1;
  u16* op0 = out + (size_t)(b * SEQ + q0) * HID + h * HD;
  u16* op1 = out + (size_t)(b * SEQ + q1) * HID + h * HD;
#pragma unroll
  for (int dt = 0; dt < 8; ++dt) {
    const u64 w0 = (u64)f2bf(o0[dt][0] * inv0) | ((u64)f2bf(o0[dt][1] * inv0) << 16)
                 | ((u64)f2bf(o0[dt][2] * inv0) << 32) | ((u64)f2bf(o0[dt][3] * inv0) << 48);
    const u64 w1 = (u64)f2bf(o1[dt][0] * inv1) | ((u64)f2bf(o1[dt][1] * inv1) << 16)
                 | ((u64)f2bf(o1[dt][2] * inv1) << 32) | ((u64)f2bf(o1[dt][3] * inv1) << 48);
    *(u64*)(op0 + dt * 16 + lg * 4) = w0;
    *(u64*)(op1 + dt * 16 + lg * 4) = w1;
  }
}

extern "C" void kernel_launch(void* const* d_in, const int* in_sizes, int n_in,
                              void* d_out, int out_size, void* d_ws, size_t ws_size,
                              hipStream_t stream) {
  (void)in_sizes; (void)n_in; (void)out_size; (void)ws_size;
  const float* x   = (const float*)d_in[0];
  const int*   pos = (const int*)d_in[1];
  // d_in[2] = mask: causal tril by construction — handled analytically
  const float* wq  = (const float*)d_in[3];
  const float* wk  = (const float*)d_in[4];
  const float* wv  = (const float*)d_in[5];
  const float* wo  = (const float*)d_in[6];
  const float* asc = (const float*)d_in[7];
  const float* fsc = (const float*)d_in[8];
  const float* w1  = (const float*)d_in[9];
  const float* w3  = (const float*)d_in[10];
  const float* w2  = (const float*)d_in[11];
  float* out = (float*)d_out;

  // workspace carve (~136 MB)
  char* ws = (char*)d_ws;
  u16* qb = (u16*)ws; ws += (size_t)MROWS * HID * 2;   // Q [B,H,S,D]
  u16* kb = (u16*)ws; ws += (size_t)MROWS * HID * 2;   // K [B,H,S,D] (contiguous after qb)
  u16* vt = (u16*)ws; ws += (size_t)MROWS * HID * 2;   // V^T [B,H,D,S] (contiguous after kb)
  u16* xb = (u16*)ws; ws += (size_t)MROWS * HID * 2;   // x_norm / attn_out / ff (bf16)
  u16* gb = (u16*)ws; ws += (size_t)MROWS * FF * 2;    // QKV fused weights, then g1/u
  u16* wb = (u16*)ws; ws += (size_t)FF * HID * 2;      // per-GEMM transposed weight

  dim3 b256(256);

  rmsnorm_k<<<MROWS, b256, 0, stream>>>(x, asc, xb);

  // fused QKV: Bt = [wq^T; wk^T; wv^T] (6144 x 2048) staged in gb (free until FFN)
  u16* gbw = gb;
  transpose_cvt_k<<<dim3(HID/32, HID/32), b256, 0, stream>>>(wq, gbw, HID, HID);
  transpose_cvt_k<<<dim3(HID/32, HID/32), b256, 0, stream>>>(wk, gbw + (size_t)HID*HID, HID, HID);
  transpose_cvt_k<<<dim3(HID/32, HID/32), b256, 0, stream>>>(wv, gbw + (size_t)2*HID*HID, HID, HID);
  gemm_k<6><<<dim3((3*HID)/128, MROWS/128), b256, 0, stream>>>(xb, gbw, 3*HID, HID, nullptr, nullptr, qb);

  rope2_k<<<(2*NB*NHD*SEQ*(HD/2))/256, b256, 0, stream>>>(qb, pos);  // qb and kb contiguous

  attn3_k<<<dim3(SEQ/128, NB*NHD), b256, 0, stream>>>(qb, kb, vt, xb);

  transpose_cvt_k<<<dim3(HID/32, HID/32), b256, 0, stream>>>(wo, wb, HID, HID);
  gemm_k<2><<<dim3(HID/128, MROWS/128), b256, 0, stream>>>(xb, wb, HID, HID, x, nullptr, out);  // h

  rmsnorm_k<<<MROWS, b256, 0, stream>>>(out, fsc, xb);  // ff

  transpose_cvt_k<<<dim3(FF/32, HID/32), b256, 0, stream>>>(w1, wb, HID, FF);
  gemm_k<3><<<dim3(FF/128, MROWS/128), b256, 0, stream>>>(xb, wb, FF, HID, nullptr, nullptr, gb);  // silu(ff@w1)
  transpose_cvt_k<<<dim3(FF/32, HID/32), b256, 0, stream>>>(w3, wb, HID, FF);
  gemm_k<4><<<dim3(FF/128, MROWS/128), b256, 0, stream>>>(xb, wb, FF, HID, nullptr, gb, gb);      // u = silu*g3
  transpose_cvt_k<<<dim3(HID/32, FF/32), b256, 0, stream>>>(w2, wb, FF, HID);
  gemm_k<2><<<dim3(HID/128, MROWS/128), b256, 0, stream>>>(gb, wb, HID, FF, out, nullptr, out);   // out = h + u@w2
}